// Round 8
// baseline (82.236 us; speedup 1.0000x reference)
//
#include <hip/hip_runtime.h>

#define QTOT 12240
#define KD   256

typedef float f32x4 __attribute__((ext_vector_type(4)));
typedef short s16x8 __attribute__((ext_vector_type(8)));
typedef unsigned short ushort_t;

__device__ __forceinline__ unsigned short f2b(float x) {
    union { float f; unsigned u; } c; c.f = x;
    unsigned r = c.u + 0x7fffu + ((c.u >> 16) & 1u);
    return (unsigned short)(r >> 16);
}
// LDS row: 512B, XOR bits 4-6 of k-byte with row&7 (write & read sides)
__device__ __forceinline__ int swz(int row, int kb) { return row * 512 + (kb ^ ((row & 7) << 4)); }

// ---------------------------------------------------------------------------
// prep: weight transpose+bf16, combined off/attn bias (unchanged, verified)
// ---------------------------------------------------------------------------
__global__ __launch_bounds__(256) void prep(
    const float* __restrict__ W_val, const float* __restrict__ W_off,
    const float* __restrict__ W_attn, const float* __restrict__ W_out,
    const float* __restrict__ b_off, const float* __restrict__ b_attn,
    ushort_t* __restrict__ WvT, ushort_t* __restrict__ WcT,
    ushort_t* __restrict__ WoT, float* __restrict__ bcomb)
{
    int id = blockIdx.x * 256 + threadIdx.x;
    if (id < 65536) { int n = id >> 8, k = id & 255; WvT[id] = f2b(W_val[k * 256 + n]); }
    else if (id < 163840) {
        int t = id - 65536; int n = t >> 8, k = t & 255;
        float v = (n < 256) ? W_off[k * 256 + n] : W_attn[k * 128 + (n - 256)];
        WcT[t] = f2b(v);
    } else if (id < 229376) {
        int t = id - 163840; int n = t >> 8, k = t & 255;
        WoT[t] = f2b(W_out[k * 256 + n]);
    } else if (id < 229760) {
        int t = id - 229376; bcomb[t] = (t < 256) ? b_off[t] : b_attn[t - 256];
    }
}

// ---------------------------------------------------------------------------
// gemm1: unchanged from R7 (verified, A-read-once, B-in-registers).
// ---------------------------------------------------------------------------
__global__ __launch_bounds__(256) void gemm1(
    const float* __restrict__ inflat, const float* __restrict__ query,
    const ushort_t* __restrict__ WvT, const ushort_t* __restrict__ WcT,
    const float* __restrict__ b_val, const float* __restrict__ bcomb,
    ushort_t* __restrict__ projb, ushort_t* __restrict__ offb,
    float* __restrict__ logitf)
{
    __shared__ char As[16384];
    const int b = blockIdx.x;
    const bool isval = b < 383;
    const int bm = (isval ? b : b - 383) * 32;
    const float* A = isval ? inflat : query;
    const ushort_t* WT = isval ? WvT : WcT;
    const int nc = isval ? 4 : 6;

    const int tid = threadIdx.x, lane = tid & 63, wave = tid >> 6;
    const int lr = lane & 15, g8 = (lane >> 4) * 8;

    {   // stage A panel: 32 rows x 256 k, f32 -> bf16, once
        const int row = tid >> 3, c0 = (tid & 7) * 32;
        const int grow = bm + row;
        if (grow < QTOT) {
            const float4* src = (const float4*)(A + (size_t)grow * KD + c0);
#pragma unroll
            for (int j = 0; j < 4; ++j) {
                float4 f0 = src[j * 2 + 0], f1 = src[j * 2 + 1];
                s16x8 v;
                v[0] = f2b(f0.x); v[1] = f2b(f0.y); v[2] = f2b(f0.z); v[3] = f2b(f0.w);
                v[4] = f2b(f1.x); v[5] = f2b(f1.y); v[6] = f2b(f1.z); v[7] = f2b(f1.w);
                *(s16x8*)(As + swz(row, (c0 + j * 8) * 2)) = v;
            }
        } else {
            s16x8 z = (s16x8)0;
#pragma unroll
            for (int j = 0; j < 4; ++j)
                *(s16x8*)(As + swz(row, (c0 + j * 8) * 2)) = z;
        }
    }
    __syncthreads();

    const int rg = (lane >> 4) * 4;

    for (int c = 0; c < nc; ++c) {
        const int col = c * 64 + wave * 16 + lr;
        s16x8 bfr[8];
        {
            const ushort_t* bp = WT + (size_t)col * KD + g8;
#pragma unroll
            for (int kc = 0; kc < 8; ++kc) bfr[kc] = *(const s16x8*)(bp + kc * 32);
        }
        f32x4 acc[2];
        acc[0] = (f32x4)0.f; acc[1] = (f32x4)0.f;
#pragma unroll
        for (int kc = 0; kc < 8; ++kc) {
            const int kb = (kc * 32 + g8) * 2;
            s16x8 a0 = *(const s16x8*)(As + swz(lr,      kb));
            s16x8 a1 = *(const s16x8*)(As + swz(16 + lr, kb));
            acc[0] = __builtin_amdgcn_mfma_f32_16x16x32_bf16(a0, bfr[kc], acc[0], 0, 0, 0);
            acc[1] = __builtin_amdgcn_mfma_f32_16x16x32_bf16(a1, bfr[kc], acc[1], 0, 0, 0);
        }
        const float bb = isval ? b_val[col] : bcomb[col];
#pragma unroll
        for (int mf = 0; mf < 2; ++mf)
#pragma unroll
            for (int rr = 0; rr < 4; ++rr) {
                const int row = bm + mf * 16 + rg + rr;
                if (row >= QTOT) continue;
                const float v = acc[mf][rr] + bb;
                if (isval)          projb[(size_t)row * 256 + col] = f2b(v);
                else if (col < 256) offb [(size_t)row * 256 + col] = f2b(v);
                else                logitf[(size_t)row * 128 + col - 256] = v;
            }
    }
}

// ---------------------------------------------------------------------------
// sample_o: fused sampling + output projection. 383 blocks x 512 threads,
// 32 queries/block. 4 sub-batches of 8 queries:
//   metadata (softmax-folded corner weights + byte-offset indices) -> LDS,
//   gathers: lane = (h, point, 8 channels); LEVELS iterated sequentially
//   per lane (keeps the GPU-wide working set ~one level -> L2-resident),
//   reduce over points via shfl, result -> swizzled bf16 LDS tile.
// Then 8 waves compute out[32x256] = tile @ W_out^T + b via MFMA with
// B fragments in registers (R7-verified pattern).
// ---------------------------------------------------------------------------
__global__ __launch_bounds__(512) void sample_o(
    const float* __restrict__ rp, const ushort_t* __restrict__ offb,
    const float* __restrict__ logitf, const ushort_t* __restrict__ projb,
    const int* __restrict__ sp, const int* __restrict__ lsi,
    const ushort_t* __restrict__ WoT, const float* __restrict__ b_out,
    float* __restrict__ out)
{
    __shared__ int   s_idx[1024][4];
    __shared__ float s_w[1024][4];
    __shared__ char  outp[16384];          // 32 rows x 512B, swizzled

    const int bid = blockIdx.x;
    const int bm = bid * 32;
    const int tid = threadIdx.x;

    for (int sb = 0; sb < 4; ++sb) {
        const int qloc0 = sb * 8;
        // ---- metadata: 1024 tasks, 2 per thread ----
#pragma unroll
        for (int rep = 0; rep < 2; ++rep) {
            const int task = rep * 512 + tid;     // (ql<<7) | t
            const int ql = task >> 7, t = task & 127;
            const int l = (t >> 2) & 3;
            int q = bm + qloc0 + ql;
            const int qc = (q < QTOT) ? q : (QTOT - 1);

            float logit = logitf[(size_t)qc * 128 + t];
            float mx = logit;
#pragma unroll
            for (int d = 1; d < 16; d <<= 1) mx = fmaxf(mx, __shfl_xor(mx, d));
            float e = __expf(logit - mx);
            float s = e;
#pragma unroll
            for (int d = 1; d < 16; d <<= 1) s += __shfl_xor(s, d);
            const float aw = e / s;

            const unsigned opk = *(const unsigned*)&offb[(size_t)qc * 256 + t * 2];
            const float ox = __uint_as_float(opk << 16);
            const float oy = __uint_as_float(opk & 0xffff0000u);

            const int Hl = sp[l * 2], Wl = sp[l * 2 + 1], st = lsi[l];
            const float rx = rp[((size_t)qc * 4 + l) * 2 + 0];
            const float ry = rp[((size_t)qc * 4 + l) * 2 + 1];

            const float x = rx * (float)Wl + ox - 0.5f;
            const float y = ry * (float)Hl + oy - 0.5f;
            const float xf = floorf(x), yf = floorf(y);
            const int x0 = (int)xf, y0 = (int)yf;
            const float lx = x - xf, ly = y - yf;

            const bool vx0 = (x0 >= 0) && (x0 < Wl);
            const bool vx1 = (x0 + 1 >= 0) && (x0 + 1 < Wl);
            const bool vy0 = (y0 >= 0) && (y0 < Hl);
            const bool vy1 = (y0 + 1 >= 0) && (y0 + 1 < Hl);

            s_w[task][0] = (vx0 && vy0) ? aw * (1.f - ly) * (1.f - lx) : 0.f;
            s_w[task][1] = (vx1 && vy0) ? aw * (1.f - ly) * lx         : 0.f;
            s_w[task][2] = (vx0 && vy1) ? aw * ly * (1.f - lx)         : 0.f;
            s_w[task][3] = (vx1 && vy1) ? aw * ly * lx                 : 0.f;
            s_idx[task][0] = (vx0 && vy0) ? (st + y0 * Wl + x0) * 512           : 0;
            s_idx[task][1] = (vx1 && vy0) ? (st + y0 * Wl + x0 + 1) * 512       : 0;
            s_idx[task][2] = (vx0 && vy1) ? (st + (y0 + 1) * Wl + x0) * 512     : 0;
            s_idx[task][3] = (vx1 && vy1) ? (st + (y0 + 1) * Wl + x0 + 1) * 512 : 0;
        }
        __syncthreads();

        // ---- gathers: 2 tasks/thread (rows ql and ql+4), levels sequential ----
        {
            const int t = tid & 127, qlA = tid >> 7;     // qlA in 0..3
            const int h = t >> 4, pq = (t >> 2) & 3, c8 = t & 3;
            const char* basec = (const char*)projb + (h * 32 + c8 * 8) * 2;

            float aA[8] = {0,0,0,0,0,0,0,0};
            float aB[8] = {0,0,0,0,0,0,0,0};
#pragma unroll
            for (int l = 0; l < 4; ++l) {
                const int slotA = (qlA << 7)       + h * 16 + l * 4 + pq;
                const int slotB = ((qlA + 4) << 7) + h * 16 + l * 4 + pq;
                const int4   iA = *(const int4*)s_idx[slotA];
                const float4 wA = *(const float4*)s_w[slotA];
                const int4   iB = *(const int4*)s_idx[slotB];
                const float4 wB = *(const float4*)s_w[slotB];
#pragma unroll
                for (int c = 0; c < 4; ++c) {
                    const int   idA = (c == 0) ? iA.x : (c == 1) ? iA.y : (c == 2) ? iA.z : iA.w;
                    const float wwA = (c == 0) ? wA.x : (c == 1) ? wA.y : (c == 2) ? wA.z : wA.w;
                    const uint4 v = *(const uint4*)(basec + idA);
                    aA[0] += wwA * __uint_as_float(v.x << 16);
                    aA[1] += wwA * __uint_as_float(v.x & 0xffff0000u);
                    aA[2] += wwA * __uint_as_float(v.y << 16);
                    aA[3] += wwA * __uint_as_float(v.y & 0xffff0000u);
                    aA[4] += wwA * __uint_as_float(v.z << 16);
                    aA[5] += wwA * __uint_as_float(v.z & 0xffff0000u);
                    aA[6] += wwA * __uint_as_float(v.w << 16);
                    aA[7] += wwA * __uint_as_float(v.w & 0xffff0000u);
                }
#pragma unroll
                for (int c = 0; c < 4; ++c) {
                    const int   idB = (c == 0) ? iB.x : (c == 1) ? iB.y : (c == 2) ? iB.z : iB.w;
                    const float wwB = (c == 0) ? wB.x : (c == 1) ? wB.y : (c == 2) ? wB.z : wB.w;
                    const uint4 v = *(const uint4*)(basec + idB);
                    aB[0] += wwB * __uint_as_float(v.x << 16);
                    aB[1] += wwB * __uint_as_float(v.x & 0xffff0000u);
                    aB[2] += wwB * __uint_as_float(v.y << 16);
                    aB[3] += wwB * __uint_as_float(v.y & 0xffff0000u);
                    aB[4] += wwB * __uint_as_float(v.z << 16);
                    aB[5] += wwB * __uint_as_float(v.z & 0xffff0000u);
                    aB[6] += wwB * __uint_as_float(v.w << 16);
                    aB[7] += wwB * __uint_as_float(v.w & 0xffff0000u);
                }
            }
            // reduce over pq (lane bits 2-3)
#pragma unroll
            for (int i = 0; i < 8; ++i) {
                aA[i] += __shfl_xor(aA[i], 4);  aA[i] += __shfl_xor(aA[i], 8);
                aB[i] += __shfl_xor(aB[i], 4);  aB[i] += __shfl_xor(aB[i], 8);
            }
            if (pq == 0) {
                const int colb = (h * 32 + c8 * 8) * 2;
                uint4 o;
                o.x = (unsigned)f2b(aA[0]) | ((unsigned)f2b(aA[1]) << 16);
                o.y = (unsigned)f2b(aA[2]) | ((unsigned)f2b(aA[3]) << 16);
                o.z = (unsigned)f2b(aA[4]) | ((unsigned)f2b(aA[5]) << 16);
                o.w = (unsigned)f2b(aA[6]) | ((unsigned)f2b(aA[7]) << 16);
                *(uint4*)(outp + swz(qloc0 + qlA, colb)) = o;
                o.x = (unsigned)f2b(aB[0]) | ((unsigned)f2b(aB[1]) << 16);
                o.y = (unsigned)f2b(aB[2]) | ((unsigned)f2b(aB[3]) << 16);
                o.z = (unsigned)f2b(aB[4]) | ((unsigned)f2b(aB[5]) << 16);
                o.w = (unsigned)f2b(aB[6]) | ((unsigned)f2b(aB[7]) << 16);
                *(uint4*)(outp + swz(qloc0 + qlA + 4, colb)) = o;
            }
        }
        __syncthreads();
    }

    // ---- output projection: out[32x256] = outp @ WoT^T + b_out ----
    const int lane = tid & 63, wave = tid >> 6;
    const int lr = lane & 15, g8 = (lane >> 4) * 8, rg = (lane >> 4) * 4;

    s16x8 bfr[2][8];
#pragma unroll
    for (int nf = 0; nf < 2; ++nf) {
        const ushort_t* bp = WoT + (size_t)(wave * 32 + nf * 16 + lr) * KD + g8;
#pragma unroll
        for (int kc = 0; kc < 8; ++kc) bfr[nf][kc] = *(const s16x8*)(bp + kc * 32);
    }

    f32x4 acc[2][2];
    acc[0][0] = (f32x4)0.f; acc[0][1] = (f32x4)0.f;
    acc[1][0] = (f32x4)0.f; acc[1][1] = (f32x4)0.f;
#pragma unroll
    for (int kc = 0; kc < 8; ++kc) {
        const int kb = (kc * 32 + g8) * 2;
        s16x8 a0 = *(const s16x8*)(outp + swz(lr,      kb));
        s16x8 a1 = *(const s16x8*)(outp + swz(16 + lr, kb));
        acc[0][0] = __builtin_amdgcn_mfma_f32_16x16x32_bf16(a0, bfr[0][kc], acc[0][0], 0, 0, 0);
        acc[1][0] = __builtin_amdgcn_mfma_f32_16x16x32_bf16(a1, bfr[0][kc], acc[1][0], 0, 0, 0);
        acc[0][1] = __builtin_amdgcn_mfma_f32_16x16x32_bf16(a0, bfr[1][kc], acc[0][1], 0, 0, 0);
        acc[1][1] = __builtin_amdgcn_mfma_f32_16x16x32_bf16(a1, bfr[1][kc], acc[1][1], 0, 0, 0);
    }

#pragma unroll
    for (int nf = 0; nf < 2; ++nf) {
        const int col = wave * 32 + nf * 16 + lr;
        const float bb = b_out[col];
#pragma unroll
        for (int mf = 0; mf < 2; ++mf)
#pragma unroll
            for (int rr = 0; rr < 4; ++rr) {
                const int row = bm + mf * 16 + rg + rr;
                if (row < QTOT) out[(size_t)row * 256 + col] = acc[mf][nf][rr] + bb;
            }
    }
}

// ---------------------------------------------------------------------------
extern "C" void kernel_launch(void* const* d_in, const int* in_sizes, int n_in,
                              void* d_out, int out_size, void* d_ws, size_t ws_size,
                              hipStream_t stream) {
    const float* query  = (const float*)d_in[0];
    const float* rp     = (const float*)d_in[1];
    const float* inflat = (const float*)d_in[2];
    const int*   sp     = (const int*)d_in[3];
    const int*   lsi    = (const int*)d_in[4];
    const float* W_off  = (const float*)d_in[5];
    const float* b_off  = (const float*)d_in[6];
    const float* W_attn = (const float*)d_in[7];
    const float* b_attn = (const float*)d_in[8];
    const float* W_val  = (const float*)d_in[9];
    const float* b_val  = (const float*)d_in[10];
    const float* W_out  = (const float*)d_in[11];
    const float* b_out  = (const float*)d_in[12];
    float* out = (float*)d_out;

    char* ws = (char*)d_ws;
    ushort_t* projb  = (ushort_t*)ws; ws += (size_t)QTOT * 256 * 2;
    ushort_t* offb   = (ushort_t*)ws; ws += (size_t)QTOT * 256 * 2;
    float*    logitf = (float*)ws;    ws += (size_t)QTOT * 128 * 4;
    ushort_t* WvT    = (ushort_t*)ws; ws += 65536 * 2;
    ushort_t* WcT    = (ushort_t*)ws; ws += 98304 * 2;
    ushort_t* WoT    = (ushort_t*)ws; ws += 65536 * 2;
    float*    bcomb  = (float*)ws;    ws += 384 * 4;

    prep<<<dim3(898), dim3(256), 0, stream>>>(W_val, W_off, W_attn, W_out, b_off, b_attn,
                                              WvT, WcT, WoT, bcomb);

    gemm1<<<dim3(766), dim3(256), 0, stream>>>(inflat, query, WvT, WcT, b_val, bcomb,
                                               projb, offb, logitf);

    sample_o<<<dim3(383), dim3(512), 0, stream>>>(rp, offb, logitf, projb, sp, lsi,
                                                  WoT, b_out, out);
}

// Round 9
// 69.937 us; speedup vs baseline: 1.1759x; 1.1759x over previous
//
#include <hip/hip_runtime.h>

#define QTOT 12240
#define KD   256

typedef float f32x4 __attribute__((ext_vector_type(4)));
typedef short s16x8 __attribute__((ext_vector_type(8)));
typedef short s16x4 __attribute__((ext_vector_type(4)));
typedef unsigned short ushort_t;

__device__ __forceinline__ unsigned short f2b(float x) {
    union { float f; unsigned u; } c; c.f = x;
    unsigned r = c.u + 0x7fffu + ((c.u >> 16) & 1u);
    return (unsigned short)(r >> 16);
}
// LDS row: 512B, XOR bits 4-6 of k-byte with row&7 (write & read sides).
// Low 4 bits of kb pass through, so 8B-aligned kb works too.
__device__ __forceinline__ int swz(int row, int kb) { return row * 512 + (kb ^ ((row & 7) << 4)); }

// ---------------------------------------------------------------------------
// prep: weight transpose+bf16, combined off/attn bias (verified)
// ---------------------------------------------------------------------------
__global__ __launch_bounds__(256) void prep(
    const float* __restrict__ W_val, const float* __restrict__ W_off,
    const float* __restrict__ W_attn, const float* __restrict__ W_out,
    const float* __restrict__ b_off, const float* __restrict__ b_attn,
    ushort_t* __restrict__ WvT, ushort_t* __restrict__ WcT,
    ushort_t* __restrict__ WoT, float* __restrict__ bcomb)
{
    int id = blockIdx.x * 256 + threadIdx.x;
    if (id < 65536) { int n = id >> 8, k = id & 255; WvT[id] = f2b(W_val[k * 256 + n]); }
    else if (id < 163840) {
        int t = id - 65536; int n = t >> 8, k = t & 255;
        float v = (n < 256) ? W_off[k * 256 + n] : W_attn[k * 128 + (n - 256)];
        WcT[t] = f2b(v);
    } else if (id < 229376) {
        int t = id - 163840; int n = t >> 8, k = t & 255;
        WoT[t] = f2b(W_out[k * 256 + n]);
    } else if (id < 229760) {
        int t = id - 229376; bcomb[t] = (t < 256) ? b_off[t] : b_attn[t - 256];
    }
}

// ---------------------------------------------------------------------------
// gemm1: R7 structure (A-read-once, B-in-registers, 1 barrier) with a
// fully-coalesced A-stage: per load inst a wave reads 1KB contiguous
// (lane-consecutive float4, wave-uniform row), LDS write is contiguous b64.
// ---------------------------------------------------------------------------
__global__ __launch_bounds__(256) void gemm1(
    const float* __restrict__ inflat, const float* __restrict__ query,
    const ushort_t* __restrict__ WvT, const ushort_t* __restrict__ WcT,
    const float* __restrict__ b_val, const float* __restrict__ bcomb,
    ushort_t* __restrict__ projb, ushort_t* __restrict__ offb,
    float* __restrict__ logitf)
{
    __shared__ char As[16384];
    const int b = blockIdx.x;
    const bool isval = b < 383;
    const int bm = (isval ? b : b - 383) * 32;
    const float* A = isval ? inflat : query;
    const ushort_t* WT = isval ? WvT : WcT;
    const int nc = isval ? 4 : 6;

    const int tid = threadIdx.x, lane = tid & 63, wave = tid >> 6;
    const int lr = lane & 15, g8 = (lane >> 4) * 8;

    {   // stage A panel: 32 rows x 256 k, f32 -> bf16; linear coalesced map
        const float4* srcb = (const float4*)(A + (size_t)bm * KD);
        const int rem_rows = QTOT - bm;
#pragma unroll
        for (int j = 0; j < 8; ++j) {
            const int f4i = j * 256 + tid;
            const int row = f4i >> 6;                 // wave-uniform
            const int colb = (f4i & 63) * 8;          // bf16 byte offset in row
            float4 f = make_float4(0.f, 0.f, 0.f, 0.f);
            if (row < rem_rows) f = srcb[f4i];
            s16x4 v;
            v[0] = f2b(f.x); v[1] = f2b(f.y); v[2] = f2b(f.z); v[3] = f2b(f.w);
            *(s16x4*)(As + swz(row, colb)) = v;
        }
    }
    __syncthreads();

    const int rg = (lane >> 4) * 4;

    for (int c = 0; c < nc; ++c) {
        const int col = c * 64 + wave * 16 + lr;
        s16x8 bfr[8];
        {
            const ushort_t* bp = WT + (size_t)col * KD + g8;
#pragma unroll
            for (int kc = 0; kc < 8; ++kc) bfr[kc] = *(const s16x8*)(bp + kc * 32);
        }
        f32x4 acc[2];
        acc[0] = (f32x4)0.f; acc[1] = (f32x4)0.f;
#pragma unroll
        for (int kc = 0; kc < 8; ++kc) {
            const int kb = (kc * 32 + g8) * 2;
            s16x8 a0 = *(const s16x8*)(As + swz(lr,      kb));
            s16x8 a1 = *(const s16x8*)(As + swz(16 + lr, kb));
            acc[0] = __builtin_amdgcn_mfma_f32_16x16x32_bf16(a0, bfr[kc], acc[0], 0, 0, 0);
            acc[1] = __builtin_amdgcn_mfma_f32_16x16x32_bf16(a1, bfr[kc], acc[1], 0, 0, 0);
        }
        const float bb = isval ? b_val[col] : bcomb[col];
#pragma unroll
        for (int mf = 0; mf < 2; ++mf)
#pragma unroll
            for (int rr = 0; rr < 4; ++rr) {
                const int row = bm + mf * 16 + rg + rr;
                if (row >= QTOT) continue;
                const float v = acc[mf][rr] + bb;
                if (isval)          projb[(size_t)row * 256 + col] = f2b(v);
                else if (col < 256) offb [(size_t)row * 256 + col] = f2b(v);
                else                logitf[(size_t)row * 128 + col - 256] = v;
            }
    }
}

// ---------------------------------------------------------------------------
// sample5: 4 queries/block, 256 threads, grid 3060. Metadata for 512 slots
// (2 reps), one barrier, then 2 gather tasks/thread = 32 independent 16B
// loads in flight. Levels iterated sequentially. 16KB LDS.
// ---------------------------------------------------------------------------
__global__ __launch_bounds__(256) void sample5(
    const float* __restrict__ rp, const ushort_t* __restrict__ offb,
    const float* __restrict__ logitf, const ushort_t* __restrict__ projb,
    const int* __restrict__ sp, const int* __restrict__ lsi,
    ushort_t* __restrict__ outpre)
{
    const int q0 = blockIdx.x * 4;
    const int tid = threadIdx.x;

    __shared__ int   s_idx[512][4];
    __shared__ float s_w[512][4];

#pragma unroll
    for (int rep = 0; rep < 2; ++rep) {
        const int task = rep * 256 + tid;
        const int ql = task >> 7, t = task & 127;
        const int l = (t >> 2) & 3;
        const int q = q0 + ql;

        float logit = logitf[(size_t)q * 128 + t];
        float mx = logit;
#pragma unroll
        for (int d = 1; d < 16; d <<= 1) mx = fmaxf(mx, __shfl_xor(mx, d));
        float e = __expf(logit - mx);
        float s = e;
#pragma unroll
        for (int d = 1; d < 16; d <<= 1) s += __shfl_xor(s, d);
        const float aw = e / s;

        const unsigned opk = *(const unsigned*)&offb[(size_t)q * 256 + t * 2];
        const float ox = __uint_as_float(opk << 16);
        const float oy = __uint_as_float(opk & 0xffff0000u);

        const int Hl = sp[l * 2], Wl = sp[l * 2 + 1], st = lsi[l];
        const float rx = rp[((size_t)q * 4 + l) * 2 + 0];
        const float ry = rp[((size_t)q * 4 + l) * 2 + 1];

        const float x = rx * (float)Wl + ox - 0.5f;
        const float y = ry * (float)Hl + oy - 0.5f;
        const float xf = floorf(x), yf = floorf(y);
        const int x0 = (int)xf, y0 = (int)yf;
        const float lx = x - xf, ly = y - yf;

        const bool vx0 = (x0 >= 0) && (x0 < Wl);
        const bool vx1 = (x0 + 1 >= 0) && (x0 + 1 < Wl);
        const bool vy0 = (y0 >= 0) && (y0 < Hl);
        const bool vy1 = (y0 + 1 >= 0) && (y0 + 1 < Hl);

        s_w[task][0] = (vx0 && vy0) ? aw * (1.f - ly) * (1.f - lx) : 0.f;
        s_w[task][1] = (vx1 && vy0) ? aw * (1.f - ly) * lx         : 0.f;
        s_w[task][2] = (vx0 && vy1) ? aw * ly * (1.f - lx)         : 0.f;
        s_w[task][3] = (vx1 && vy1) ? aw * ly * lx                 : 0.f;
        s_idx[task][0] = (vx0 && vy0) ? (st + y0 * Wl + x0) * 512           : 0;
        s_idx[task][1] = (vx1 && vy0) ? (st + y0 * Wl + x0 + 1) * 512       : 0;
        s_idx[task][2] = (vx0 && vy1) ? (st + (y0 + 1) * Wl + x0) * 512     : 0;
        s_idx[task][3] = (vx1 && vy1) ? (st + (y0 + 1) * Wl + x0 + 1) * 512 : 0;
    }
    __syncthreads();

    const int t = tid & 127, qlA = tid >> 7;            // qlA in {0,1}
    const int h = t >> 4, pq = (t >> 2) & 3, c8 = t & 3;
    const char* basec = (const char*)projb + (h * 32 + c8 * 8) * 2;

    float aA[8] = {0,0,0,0,0,0,0,0};
    float aB[8] = {0,0,0,0,0,0,0,0};
#pragma unroll
    for (int l = 0; l < 4; ++l) {
        const int slotA = (qlA << 7)       + h * 16 + l * 4 + pq;
        const int slotB = ((qlA + 2) << 7) + h * 16 + l * 4 + pq;
        const int4   iA = *(const int4*)s_idx[slotA];
        const float4 wA = *(const float4*)s_w[slotA];
        const int4   iB = *(const int4*)s_idx[slotB];
        const float4 wB = *(const float4*)s_w[slotB];
#pragma unroll
        for (int c = 0; c < 4; ++c) {
            const int   idA = (c == 0) ? iA.x : (c == 1) ? iA.y : (c == 2) ? iA.z : iA.w;
            const float wwA = (c == 0) ? wA.x : (c == 1) ? wA.y : (c == 2) ? wA.z : wA.w;
            const uint4 v = *(const uint4*)(basec + idA);
            aA[0] += wwA * __uint_as_float(v.x << 16);
            aA[1] += wwA * __uint_as_float(v.x & 0xffff0000u);
            aA[2] += wwA * __uint_as_float(v.y << 16);
            aA[3] += wwA * __uint_as_float(v.y & 0xffff0000u);
            aA[4] += wwA * __uint_as_float(v.z << 16);
            aA[5] += wwA * __uint_as_float(v.z & 0xffff0000u);
            aA[6] += wwA * __uint_as_float(v.w << 16);
            aA[7] += wwA * __uint_as_float(v.w & 0xffff0000u);
        }
#pragma unroll
        for (int c = 0; c < 4; ++c) {
            const int   idB = (c == 0) ? iB.x : (c == 1) ? iB.y : (c == 2) ? iB.z : iB.w;
            const float wwB = (c == 0) ? wB.x : (c == 1) ? wB.y : (c == 2) ? wB.z : wB.w;
            const uint4 v = *(const uint4*)(basec + idB);
            aB[0] += wwB * __uint_as_float(v.x << 16);
            aB[1] += wwB * __uint_as_float(v.x & 0xffff0000u);
            aB[2] += wwB * __uint_as_float(v.y << 16);
            aB[3] += wwB * __uint_as_float(v.y & 0xffff0000u);
            aB[4] += wwB * __uint_as_float(v.z << 16);
            aB[5] += wwB * __uint_as_float(v.z & 0xffff0000u);
            aB[6] += wwB * __uint_as_float(v.w << 16);
            aB[7] += wwB * __uint_as_float(v.w & 0xffff0000u);
        }
    }
#pragma unroll
    for (int i = 0; i < 8; ++i) {
        aA[i] += __shfl_xor(aA[i], 4);  aA[i] += __shfl_xor(aA[i], 8);
        aB[i] += __shfl_xor(aB[i], 4);  aB[i] += __shfl_xor(aB[i], 8);
    }
    if (pq == 0) {
        const int colo = h * 32 + c8 * 8;
        uint4 o;
        o.x = (unsigned)f2b(aA[0]) | ((unsigned)f2b(aA[1]) << 16);
        o.y = (unsigned)f2b(aA[2]) | ((unsigned)f2b(aA[3]) << 16);
        o.z = (unsigned)f2b(aA[4]) | ((unsigned)f2b(aA[5]) << 16);
        o.w = (unsigned)f2b(aA[6]) | ((unsigned)f2b(aA[7]) << 16);
        *(uint4*)&outpre[(size_t)(q0 + qlA) * 256 + colo] = o;
        o.x = (unsigned)f2b(aB[0]) | ((unsigned)f2b(aB[1]) << 16);
        o.y = (unsigned)f2b(aB[2]) | ((unsigned)f2b(aB[3]) << 16);
        o.z = (unsigned)f2b(aB[4]) | ((unsigned)f2b(aB[5]) << 16);
        o.w = (unsigned)f2b(aB[6]) | ((unsigned)f2b(aB[7]) << 16);
        *(uint4*)&outpre[(size_t)(q0 + qlA + 2) * 256 + colo] = o;
    }
}

// ---------------------------------------------------------------------------
// gemm_o: LDS-free, barrier-free (verified R7). 383 blocks, BM=32, N=256.
// ---------------------------------------------------------------------------
__global__ __launch_bounds__(256) void gemm_o(
    const ushort_t* __restrict__ Ab, const ushort_t* __restrict__ WoT,
    const float* __restrict__ b_out, float* __restrict__ out)
{
    const int bm = blockIdx.x * 32;
    const int tid = threadIdx.x, lane = tid & 63, wave = tid >> 6;
    const int lr = lane & 15, g8 = (lane >> 4) * 8;
    const int rg = (lane >> 4) * 4;

    const ushort_t* ap0;
    const ushort_t* ap1;
    {
        int r0 = bm + lr;      if (r0 >= QTOT) r0 = QTOT - 1;
        int r1 = bm + 16 + lr; if (r1 >= QTOT) r1 = QTOT - 1;
        ap0 = Ab + (size_t)r0 * KD + g8;
        ap1 = Ab + (size_t)r1 * KD + g8;
    }

#pragma unroll
    for (int c = 0; c < 4; ++c) {
        const int col = c * 64 + wave * 16 + lr;
        s16x8 bfr[8];
        {
            const ushort_t* bp = WoT + (size_t)col * KD + g8;
#pragma unroll
            for (int kc = 0; kc < 8; ++kc) bfr[kc] = *(const s16x8*)(bp + kc * 32);
        }
        f32x4 acc[2];
        acc[0] = (f32x4)0.f; acc[1] = (f32x4)0.f;
#pragma unroll
        for (int kc = 0; kc < 8; ++kc) {
            s16x8 a0 = *(const s16x8*)(ap0 + kc * 32);
            s16x8 a1 = *(const s16x8*)(ap1 + kc * 32);
            acc[0] = __builtin_amdgcn_mfma_f32_16x16x32_bf16(a0, bfr[kc], acc[0], 0, 0, 0);
            acc[1] = __builtin_amdgcn_mfma_f32_16x16x32_bf16(a1, bfr[kc], acc[1], 0, 0, 0);
        }
        const float bb = b_out[col];
#pragma unroll
        for (int mf = 0; mf < 2; ++mf)
#pragma unroll
            for (int rr = 0; rr < 4; ++rr) {
                const int row = bm + mf * 16 + rg + rr;
                if (row < QTOT) out[(size_t)row * 256 + col] = acc[mf][rr] + bb;
            }
    }
}

// ---------------------------------------------------------------------------
extern "C" void kernel_launch(void* const* d_in, const int* in_sizes, int n_in,
                              void* d_out, int out_size, void* d_ws, size_t ws_size,
                              hipStream_t stream) {
    const float* query  = (const float*)d_in[0];
    const float* rp     = (const float*)d_in[1];
    const float* inflat = (const float*)d_in[2];
    const int*   sp     = (const int*)d_in[3];
    const int*   lsi    = (const int*)d_in[4];
    const float* W_off  = (const float*)d_in[5];
    const float* b_off  = (const float*)d_in[6];
    const float* W_attn = (const float*)d_in[7];
    const float* b_attn = (const float*)d_in[8];
    const float* W_val  = (const float*)d_in[9];
    const float* b_val  = (const float*)d_in[10];
    const float* W_out  = (const float*)d_in[11];
    const float* b_out  = (const float*)d_in[12];
    float* out = (float*)d_out;

    char* ws = (char*)d_ws;
    ushort_t* projb  = (ushort_t*)ws; ws += (size_t)QTOT * 256 * 2;
    ushort_t* offb   = (ushort_t*)ws; ws += (size_t)QTOT * 256 * 2;
    float*    logitf = (float*)ws;    ws += (size_t)QTOT * 128 * 4;
    ushort_t* outpre = (ushort_t*)ws; ws += (size_t)QTOT * 256 * 2;
    ushort_t* WvT    = (ushort_t*)ws; ws += 65536 * 2;
    ushort_t* WcT    = (ushort_t*)ws; ws += 98304 * 2;
    ushort_t* WoT    = (ushort_t*)ws; ws += 65536 * 2;
    float*    bcomb  = (float*)ws;    ws += 384 * 4;

    prep<<<dim3(898), dim3(256), 0, stream>>>(W_val, W_off, W_attn, W_out, b_off, b_attn,
                                              WvT, WcT, WoT, bcomb);

    gemm1<<<dim3(766), dim3(256), 0, stream>>>(inflat, query, WvT, WcT, b_val, bcomb,
                                               projb, offb, logitf);

    sample5<<<dim3(3060), dim3(256), 0, stream>>>(rp, offb, logitf, projb, sp, lsi, outpre);

    gemm_o<<<dim3(383), dim3(256), 0, stream>>>(outpre, WoT, b_out, out);
}